// Round 4
// baseline (1232.653 us; speedup 1.0000x reference)
//
#include <hip/hip_runtime.h>
#include <hip/hip_bf16.h>

// ---------------------------------------------------------------------------
// D-MPNN molecule encoder, round 3: latency-fixed MFMA GEMM.
//
// R2 postmortem: K-loop had {gathered A load -> LDS -> barrier -> MFMA ->
// barrier} x8 => every iteration paid a full un-hidden gather latency
// (~8.5k cyc/iter). Fix:
//   * stage the FULL A tile (64 x Kp) once at block start (all loads in
//     flight together), single __syncthreads;
//   * B (weights) read directly from L2-resident Wt[N][Kp] into fragments --
//     no LDS, no barriers in the K-loop at all.
// ---------------------------------------------------------------------------

typedef __hip_bfloat16 bf16;
typedef __attribute__((ext_vector_type(8))) short short8;
typedef __attribute__((ext_vector_type(4))) float f32x4;

__device__ __forceinline__ float b2f(bf16 x) { return __bfloat162float(x); }
__device__ __forceinline__ bf16  f2b(float x) { return __float2bfloat16(x); }
__device__ __forceinline__ float bs2f(short s) {
    unsigned int u = ((unsigned int)(unsigned short)s) << 16;
    float f; __builtin_memcpy(&f, &u, 4); return f;
}
__device__ __forceinline__ short f2bs(float f) {
    bf16 b = __float2bfloat16(f);
    short s; __builtin_memcpy(&s, &b, 2); return s;
}

#define BM 64

enum { AM_F32 = 0, AM_DIFF = 1, AM_CONCAT = 2 };
enum { OM_PRE = 0, OM_RELU = 1 };

// N fixed at 256. Wt: [256][KP] bf16, k-contiguous, zero-padded K..KP.
// LDS row stride KP+8 shorts: keeps 16B alignment, 2-way bank alias (free).
template <int MODE, int OUT, int KP>
__global__ __launch_bounds__(256) void mfma_gemm(
    int M, int K, int K1,
    const float* __restrict__ Af,    // AM_F32: [M,K]; AM_CONCAT: [M,K1]
    const bf16* __restrict__ Ab1,    // AM_DIFF: amsg; AM_CONCAT: [M,K-K1]
    const bf16* __restrict__ Ab2,    // AM_DIFF: msg
    const int* __restrict__ g1,
    const int* __restrict__ g2,
    const bf16* __restrict__ Wt,     // [256][KP]
    const float* __restrict__ bias,  // [256] or null
    const bf16* __restrict__ addC,   // [M,256] or null (pre-relu residual)
    bf16* __restrict__ out)          // [M,256]
{
    constexpr int LDA = KP + 8;
    __shared__ bf16 As[BM * LDA];

    const int t    = threadIdx.x;
    const int wave = t >> 6;
    const int lane = t & 63;
    const int bm   = blockIdx.x * BM;

    // ---------------- stage FULL A tile: 64 rows x KP, once ----------------
    {
        const int srow = t >> 2;          // 4 threads per row
        const int scol = (t & 3) * 8;     // 8-k slice within each 32-k chunk
        const int arow = bm + srow;
        int r1 = 0, r2 = 0;
        if (MODE == AM_DIFF && arow < M) { r1 = g1[arow]; r2 = g2[arow]; }

        #pragma unroll
        for (int j = 0; j < KP / 32; j++) {
            const int kbase = j * 32 + scol;
            short8 av = {};
            if (arow < M) {
                if (MODE == AM_DIFF) {
                    // K == KP == 256, rows 16B-aligned: vector fast path
                    const short8 x1 = *(const short8*)(Ab1 + (size_t)r1 * KP + kbase);
                    const short8 x2 = *(const short8*)(Ab2 + (size_t)r2 * KP + kbase);
                    #pragma unroll
                    for (int jj = 0; jj < 8; jj++)
                        av[jj] = f2bs(bs2f(x1[jj]) - fmaxf(bs2f(x2[jj]), 0.f));
                } else if (MODE == AM_F32) {
                    // rows are K floats (not 16B aligned) -> scalar loads
                    #pragma unroll
                    for (int jj = 0; jj < 8; jj++) {
                        int k = kbase + jj;
                        av[jj] = (k < K) ? f2bs(Af[(size_t)arow * K + k]) : short(0);
                    }
                } else { // AM_CONCAT: [f32 K1 | bf16 K-K1]
                    #pragma unroll
                    for (int jj = 0; jj < 8; jj++) {
                        int k = kbase + jj;
                        float v = 0.f;
                        if (k < K) {
                            v = (k < K1) ? Af[(size_t)arow * K1 + k]
                                         : b2f(Ab1[(size_t)arow * (K - K1) + (k - K1)]);
                        }
                        av[jj] = f2bs(v);
                    }
                }
            }
            *(short8*)&As[srow * LDA + kbase] = av;
        }
    }
    __syncthreads();   // the ONLY barrier

    // ---------------- barrier-free K loop ----------------
    const int mrow = lane & 15;
    const int koff = (lane >> 4) * 8;
    const bf16* WtW = Wt + (size_t)(wave * 64 + mrow) * KP;

    f32x4 acc[4][4] = {};

    #pragma unroll 2
    for (int k0 = 0; k0 < KP; k0 += 32) {
        short8 afrag[4], bfrag[4];
        #pragma unroll
        for (int tn = 0; tn < 4; tn++)
            bfrag[tn] = *(const short8*)(WtW + (size_t)tn * 16 * KP + k0 + koff);
        #pragma unroll
        for (int tm = 0; tm < 4; tm++)
            afrag[tm] = *(const short8*)&As[(tm * 16 + mrow) * LDA + k0 + koff];
        #pragma unroll
        for (int tm = 0; tm < 4; tm++)
            #pragma unroll
            for (int tn = 0; tn < 4; tn++)
                acc[tm][tn] = __builtin_amdgcn_mfma_f32_16x16x32_bf16(
                    afrag[tm], bfrag[tn], acc[tm][tn], 0, 0, 0);
    }

    // ---------------- epilogue: C/D col=lane&15, row=(lane>>4)*4+reg -------
    #pragma unroll
    for (int tm = 0; tm < 4; tm++) {
        #pragma unroll
        for (int r = 0; r < 4; r++) {
            int row = bm + tm * 16 + (lane >> 4) * 4 + r;
            if (row >= M) continue;
            #pragma unroll
            for (int tn = 0; tn < 4; tn++) {
                int col = wave * 64 + tn * 16 + (lane & 15);
                float v = acc[tm][tn][r];
                if (bias) v += bias[col];
                size_t o = (size_t)row * 256 + col;
                if (addC) v += b2f(addC[o]);  // same-thread read-before-write when aliased
                if (OUT == OM_RELU) v = fmaxf(v, 0.f);
                out[o] = f2b(v);
            }
        }
    }
}

// W[K][256] f32 -> Wt[256][Kp] bf16 (zero pad k in [K,Kp))
__global__ __launch_bounds__(256) void convert_wt(
    const float* __restrict__ W, bf16* __restrict__ Wt, int K, int Kp)
{
    int i = blockIdx.x * 256 + threadIdx.x;
    if (i >= 256 * Kp) return;
    int n = i / Kp, k = i - n * Kp;
    Wt[i] = (k < K) ? f2b(W[(size_t)k * 256 + n]) : f2b(0.f);
}

// amsg[a, c..c+8) = sum_k relu(msg[a2b[a,k], c..c+8)); 16B loads, 32 thr/atom
__global__ __launch_bounds__(256) void gather_sum8(
    const bf16* __restrict__ msg, const int* __restrict__ a2b,
    bf16* __restrict__ amsg, int A)
{
    int idx = blockIdx.x * 256 + threadIdx.x;
    if (idx >= A * 32) return;
    int a = idx >> 5;
    int c = (idx & 31) * 8;
    const int* nb = a2b + (size_t)a * 6;
    float s[8] = {};
    #pragma unroll
    for (int k = 0; k < 6; k++) {
        const short8 v = *(const short8*)(msg + (size_t)nb[k] * 256 + c);
        #pragma unroll
        for (int j = 0; j < 8; j++) s[j] += fmaxf(bs2f(v[j]), 0.f);
    }
    short8 o;
    #pragma unroll
    for (int j = 0; j < 8; j++) o[j] = f2bs(s[j]);
    *(short8*)(amsg + (size_t)a * 256 + c) = o;
}

// molv[m,h] = mean over the sorted segment atom2mol==m (0 if empty)
__global__ __launch_bounds__(256) void segment_mean_kernel(
    const bf16* __restrict__ ah, const int* __restrict__ atom2mol,
    int A, float* __restrict__ molv)
{
    int m = blockIdx.x;
    int h = threadIdx.x;
    int lo = 0, hi = A;
    while (lo < hi) { int mid = (lo + hi) >> 1; if (atom2mol[mid] < m) lo = mid + 1; else hi = mid; }
    int start = lo;
    hi = A;
    while (lo < hi) { int mid = (lo + hi) >> 1; if (atom2mol[mid] <= m) lo = mid + 1; else hi = mid; }
    int end = lo;
    float s = 0.f;
    for (int a = start; a < end; a++) s += b2f(ah[(size_t)a * 256 + h]);
    float cnt = (float)(end - start);
    molv[(size_t)m * 256 + h] = s / fmaxf(cnt, 1.f);
}

// fp32 vector GEMM for the small MLP: C = relu([A1|A2] @ W + bias)
#define TM 64
#define TN 64
#define TK 16
__global__ __launch_bounds__(256) void gemm_f32(
    int M, int N, int K, int K1,
    const float* __restrict__ Af1,
    const float* __restrict__ Af2,
    const float* __restrict__ W,
    const float* __restrict__ bias,
    float* __restrict__ outF)
{
    __shared__ float As[TK][TM + 4];
    __shared__ float Bs[TK][TN + 4];
    const int bm = blockIdx.x * TM;
    const int bn = blockIdx.y * TN;
    const int t  = threadIdx.x;
    const int tx = t & 15;
    const int ty = t >> 4;
    float acc[4][4] = {};
    for (int k0 = 0; k0 < K; k0 += TK) {
        #pragma unroll
        for (int i = 0; i < 4; i++) {
            int idx = t + i * 256;
            int r = idx >> 4, kk = idx & 15;
            int row = bm + r, k = k0 + kk;
            float v = 0.f;
            if (row < M && k < K)
                v = (k < K1) ? Af1[(size_t)row * K1 + k]
                             : Af2[(size_t)row * (K - K1) + (k - K1)];
            As[kk][r] = v;
        }
        #pragma unroll
        for (int i = 0; i < 4; i++) {
            int idx = t + i * 256;
            int nn = idx & 63, kk = idx >> 6;
            int k = k0 + kk, n = bn + nn;
            float v = 0.f;
            if (k < K && n < N) v = W[(size_t)k * N + n];
            Bs[kk][nn] = v;
        }
        __syncthreads();
        #pragma unroll
        for (int kk = 0; kk < TK; kk++) {
            float a[4], b[4];
            #pragma unroll
            for (int i = 0; i < 4; i++) a[i] = As[kk][ty * 4 + i];
            #pragma unroll
            for (int j = 0; j < 4; j++) b[j] = Bs[kk][tx * 4 + j];
            #pragma unroll
            for (int i = 0; i < 4; i++)
                #pragma unroll
                for (int j = 0; j < 4; j++)
                    acc[i][j] += a[i] * b[j];
        }
        __syncthreads();
    }
    #pragma unroll
    for (int i = 0; i < 4; i++) {
        int row = bm + ty * 4 + i;
        if (row >= M) continue;
        #pragma unroll
        for (int j = 0; j < 4; j++) {
            int n = bn + tx * 4 + j;
            if (n >= N) continue;
            float v = acc[i][j] + (bias ? bias[n] : 0.f);
            outF[(size_t)row * N + n] = fmaxf(v, 0.f);
        }
    }
}

extern "C" void kernel_launch(void* const* d_in, const int* in_sizes, int n_in,
                              void* d_out, int out_size, void* d_ws, size_t ws_size,
                              hipStream_t stream)
{
    const float* f_atoms  = (const float*)d_in[0];
    const float* f_bonds  = (const float*)d_in[1];
    const int*   a2b      = (const int*)d_in[2];
    const int*   b2a      = (const int*)d_in[3];
    const int*   b2revb   = (const int*)d_in[4];
    const int*   atom2mol = (const int*)d_in[5];
    const float* mol_feat = (const float*)d_in[6];
    const float* W_i      = (const float*)d_in[7];
    const float* W_h      = (const float*)d_in[8];
    const float* W_o_w    = (const float*)d_in[9];
    const float* W_o_b    = (const float*)d_in[10];
    const float* W1       = (const float*)d_in[11];
    const float* b1       = (const float*)d_in[12];
    const float* W2       = (const float*)d_in[13];
    const float* b2       = (const float*)d_in[14];

    const int A  = 100000, B = 200000, H = 256;
    const int AF = 133, BF = 147;
    const int NM = 4096, MF = 200, FH = 512, EH = 256;
    const int KpI = 160, KpH = 256, KpO = 416;

    char* ws = (char*)d_ws;
    bf16* buf0 = (bf16*)ws;  ws += (size_t)B * H * sizeof(bf16);     // 102.4 MB
    bf16* buf1 = (bf16*)ws;  ws += (size_t)B * H * sizeof(bf16);     // 102.4 MB
    bf16* amsg = (bf16*)ws;  ws += (size_t)A * H * sizeof(bf16);     //  51.2 MB
    float* molv = (float*)ws; ws += (size_t)NM * H * sizeof(float);  //   4 MB
    float* hbuf = (float*)ws; ws += (size_t)NM * FH * sizeof(float); //   8 MB
    bf16* WtI = (bf16*)ws;   ws += (size_t)256 * KpI * sizeof(bf16);
    bf16* WtH = (bf16*)ws;   ws += (size_t)256 * KpH * sizeof(bf16);
    bf16* WtO = (bf16*)ws;   ws += (size_t)256 * KpO * sizeof(bf16);

    dim3 blk(256);
    const int gsB = (B + BM - 1) / BM;      // 3125
    const int gsA = (A + BM - 1) / BM;      // 1563
    const int gsG = (A * 32 + 255) / 256;   // 12500

    // 0. pre-transpose/convert weights to bf16 [256][Kp]
    convert_wt<<<dim3((256 * KpI + 255) / 256), blk, 0, stream>>>(W_i, WtI, BF, KpI);
    convert_wt<<<dim3((256 * KpH + 255) / 256), blk, 0, stream>>>(W_h, WtH, H, KpH);
    convert_wt<<<dim3((256 * KpO + 255) / 256), blk, 0, stream>>>(W_o_w, WtO, AF + H, KpO);

    // 1. buf0 = f_bonds @ W_i  (pre-relu)
    mfma_gemm<AM_F32, OM_PRE, 160><<<dim3(gsB), blk, 0, stream>>>(
        B, BF, BF, f_bonds, nullptr, nullptr, nullptr, nullptr,
        WtI, nullptr, nullptr, buf0);

    // 2a. iter 1 (rev-gather source buf0; relu-on-read makes it msg0)
    gather_sum8<<<dim3(gsG), blk, 0, stream>>>(buf0, a2b, amsg, A);
    mfma_gemm<AM_DIFF, OM_RELU, 256><<<dim3(gsB), blk, 0, stream>>>(
        B, H, H, nullptr, amsg, buf0, b2a, b2revb,
        WtH, nullptr, buf0, buf1);

    // 2b. iter 2 (in-place into buf0; residual read same-thread pre-write)
    gather_sum8<<<dim3(gsG), blk, 0, stream>>>(buf1, a2b, amsg, A);
    mfma_gemm<AM_DIFF, OM_RELU, 256><<<dim3(gsB), blk, 0, stream>>>(
        B, H, H, nullptr, amsg, buf1, b2a, b2revb,
        WtH, nullptr, buf0, buf0);

    // 3. final neighbor sum (relu-on-read idempotent)
    gather_sum8<<<dim3(gsG), blk, 0, stream>>>(buf0, a2b, amsg, A);

    // 4. buf1 = relu([f_atoms | amsg] @ W_o_w + b)
    mfma_gemm<AM_CONCAT, OM_RELU, 416><<<dim3(gsA), blk, 0, stream>>>(
        A, AF + H, AF, f_atoms, amsg, nullptr, nullptr, nullptr,
        WtO, W_o_b, nullptr, buf1);

    // 5. per-molecule mean
    segment_mean_kernel<<<dim3(NM), blk, 0, stream>>>(buf1, atom2mol, A, molv);

    // 6. hbuf = relu([molv | mol_feat] @ W1 + b1)
    gemm_f32<<<dim3((NM + TM - 1) / TM, FH / TN), blk, 0, stream>>>(
        NM, FH, H + MF, H, molv, mol_feat, W1, b1, hbuf);

    // 7. out = relu(hbuf @ W2 + b2)
    gemm_f32<<<dim3((NM + TM - 1) / TM, EH / TN), blk, 0, stream>>>(
        NM, EH, FH, FH, hbuf, nullptr, W2, b2, (float*)d_out);
}

// Round 5
// 1231.960 us; speedup vs baseline: 1.0006x; 1.0006x over previous
//
#include <hip/hip_runtime.h>
#include <hip/hip_bf16.h>

// ---------------------------------------------------------------------------
// D-MPNN molecule encoder, round 4: wave-private MFMA GEMM, zero main-path
// barriers, vectorized epilogue, MFMA MLP.
//
// R3 postmortem: latency-bound (MfmaUtil 5%), occupancy 19.5%, staging burst
// + single barrier serialized everything; scalar 2-B epilogue. HBM-bound
// floor per big GEMM ~66 us; we were at 201.
//
// New GEMM structure (256 thr = 4 waves):
//   wave (wm,wn) owns M rows [bm+wm*32, +32) x N cols [n0+wn*128, +128)
//   A fragments live in registers (2 M-tiles x 4 chunks in flight),
//   B fragments streamed from L2-resident Wt[N][KP], reused across M-tiles.
//   No LDS / no barriers until the epilogue transpose.
// ---------------------------------------------------------------------------

typedef __hip_bfloat16 bf16;
typedef __attribute__((ext_vector_type(8))) short short8;
typedef __attribute__((ext_vector_type(4))) float f32x4;

__device__ __forceinline__ float b2f(bf16 x) { return __bfloat162float(x); }
__device__ __forceinline__ bf16  f2b(float x) { return __float2bfloat16(x); }
__device__ __forceinline__ float bs2f(short s) {
    unsigned int u = ((unsigned int)(unsigned short)s) << 16;
    float f; __builtin_memcpy(&f, &u, 4); return f;
}
__device__ __forceinline__ short f2bs(float f) {
    bf16 b = __float2bfloat16(f);
    short s; __builtin_memcpy(&s, &b, 2); return s;
}

enum { AM_F32 = 0, AM_DIFF = 1, AM_CONCAT_FB = 2, AM_CONCAT_FF = 3, AM_BF16 = 4 };
enum { OM_PRE_B = 0, OM_RELU_B = 1, OM_RELU_F = 2 };

// Block covers 64 M x 256 N. Grid: (ceil(M/64), Ntotal/256).
// Wt: [Ntotal][KP] bf16, k-contiguous, zero-padded K..KP.
template <int MODE, int OUT, int KP>
__global__ __launch_bounds__(256, 2) void mfma_gemm(
    int M, int K, int K1, int ldOut,
    const float* __restrict__ Af,    // F32:[M,K]; CONCAT_*: [M,K1]
    const float* __restrict__ Af2,   // CONCAT_FF: [M,K-K1]
    const bf16* __restrict__ Ab1,    // DIFF: amsg[*,KP]; CONCAT_FB: [M,K-K1]; BF16: [M,KP]
    const bf16* __restrict__ Ab2,    // DIFF: msg[*,KP]
    const int* __restrict__ g1,
    const int* __restrict__ g2,
    const bf16* __restrict__ Wt,
    const float* __restrict__ bias,  // [Ntotal] or null
    const bf16* __restrict__ addC,   // [M,ldOut] or null (pre-relu residual)
    bf16* __restrict__ outB,
    float* __restrict__ outF)
{
    constexpr int CH = KP / 32;          // 32-k chunks
    constexpr int NG = (CH + 3) / 4;     // groups of <=4 chunks

    __shared__ bf16 eps[4 * 32 * 136];   // epilogue transpose, 34816 B

    const int t    = threadIdx.x;
    const int wave = t >> 6;
    const int lane = t & 63;
    const int wm   = wave & 1;
    const int wn   = wave >> 1;
    const int m    = lane & 15;
    const int q    = lane >> 4;
    const int bm   = blockIdx.x * 64;
    const int n0   = blockIdx.y * 256 + wn * 128;

    int rowA[2], r1[2], r2[2];
    #pragma unroll
    for (int tm = 0; tm < 2; tm++) {
        rowA[tm] = bm + wm * 32 + tm * 16 + m;
        if (MODE == AM_DIFF) {
            const bool ok = rowA[tm] < M;
            r1[tm] = ok ? g1[rowA[tm]] : 0;
            r2[tm] = ok ? g2[rowA[tm]] : 0;
        }
    }

    f32x4 acc[2][8] = {};

    #pragma unroll
    for (int g = 0; g < NG; g++) {
        const int c0 = g * 4;
        // ---- load A fragments for this chunk-group into registers ----
        short8 af[2][4];
        #pragma unroll
        for (int tm = 0; tm < 2; tm++) {
            #pragma unroll
            for (int c = 0; c < 4; c++) {
                if (c0 + c >= CH) continue;
                const int kb = (c0 + c) * 32 + q * 8;
                short8 av = {};
                if (MODE == AM_DIFF) {
                    const short8 x1 = *(const short8*)(Ab1 + (size_t)r1[tm] * KP + kb);
                    const short8 x2 = *(const short8*)(Ab2 + (size_t)r2[tm] * KP + kb);
                    #pragma unroll
                    for (int j = 0; j < 8; j++)
                        av[j] = f2bs(bs2f(x1[j]) - fmaxf(bs2f(x2[j]), 0.f));
                } else if (MODE == AM_BF16) {
                    if (rowA[tm] < M)
                        av = *(const short8*)(Ab1 + (size_t)rowA[tm] * KP + kb);
                } else if (MODE == AM_F32) {
                    if (rowA[tm] < M) {
                        #pragma unroll
                        for (int j = 0; j < 8; j++) {
                            int k = kb + j;
                            av[j] = (k < K) ? f2bs(Af[(size_t)rowA[tm] * K + k]) : short(0);
                        }
                    }
                } else if (MODE == AM_CONCAT_FB) {
                    if (rowA[tm] < M) {
                        #pragma unroll
                        for (int j = 0; j < 8; j++) {
                            int k = kb + j;
                            float v = 0.f;
                            if (k < K1) v = Af[(size_t)rowA[tm] * K1 + k];
                            else if (k < K) v = b2f(Ab1[(size_t)rowA[tm] * (K - K1) + (k - K1)]);
                            av[j] = f2bs(v);
                        }
                    }
                } else { // AM_CONCAT_FF
                    if (rowA[tm] < M) {
                        #pragma unroll
                        for (int j = 0; j < 8; j++) {
                            int k = kb + j;
                            float v = 0.f;
                            if (k < K1) v = Af[(size_t)rowA[tm] * K1 + k];
                            else if (k < K) v = Af2[(size_t)rowA[tm] * (K - K1) + (k - K1)];
                            av[j] = f2bs(v);
                        }
                    }
                }
                af[tm][c] = av;
            }
        }
        // ---- stream B from L2, 2 MFMAs per fragment (reused across tm) ----
        #pragma unroll
        for (int tn = 0; tn < 8; tn++) {
            #pragma unroll
            for (int c = 0; c < 4; c++) {
                if (c0 + c >= CH) continue;
                const short8 bfr = *(const short8*)(
                    Wt + (size_t)(n0 + tn * 16 + m) * KP + (c0 + c) * 32 + q * 8);
                acc[0][tn] = __builtin_amdgcn_mfma_f32_16x16x32_bf16(
                    af[0][c], bfr, acc[0][tn], 0, 0, 0);
                acc[1][tn] = __builtin_amdgcn_mfma_f32_16x16x32_bf16(
                    af[1][c], bfr, acc[1][tn], 0, 0, 0);
            }
        }
    }

    // ---- epilogue; C/D layout: col=lane&15, row=(lane>>4)*4+reg ----
    if (OUT == OM_RELU_F) {
        #pragma unroll
        for (int tm = 0; tm < 2; tm++) {
            #pragma unroll
            for (int r = 0; r < 4; r++) {
                const int row = bm + wm * 32 + tm * 16 + q * 4 + r;
                if (row >= M) continue;
                #pragma unroll
                for (int tn = 0; tn < 8; tn++) {
                    const int col = n0 + tn * 16 + m;
                    float v = acc[tm][tn][r] + (bias ? bias[col] : 0.f);
                    outF[(size_t)row * ldOut + col] = fmaxf(v, 0.f);
                }
            }
        }
    } else {
        // stage acc into per-wave LDS slice (rows padded to 136 shorts)
        bf16* lds = eps + wave * 32 * 136;
        #pragma unroll
        for (int tm = 0; tm < 2; tm++)
            #pragma unroll
            for (int tn = 0; tn < 8; tn++)
                #pragma unroll
                for (int r = 0; r < 4; r++)
                    lds[(tm * 16 + q * 4 + r) * 136 + tn * 16 + m] =
                        f2b(acc[tm][tn][r]);
        __syncthreads();
        // coalesced readback: lane covers (row = p*4+q, cols m*8..m*8+8)
        #pragma unroll
        for (int p = 0; p < 8; p++) {
            const int lr  = p * 4 + q;
            const int row = bm + wm * 32 + lr;
            if (row >= M) continue;
            const int col = n0 + m * 8;
            const short8 v = *(const short8*)&lds[lr * 136 + m * 8];
            float vf[8];
            #pragma unroll
            for (int j = 0; j < 8; j++) vf[j] = bs2f(v[j]);
            if (bias) {
                const f32x4 b0 = *(const f32x4*)(bias + col);
                const f32x4 b1v = *(const f32x4*)(bias + col + 4);
                #pragma unroll
                for (int j = 0; j < 4; j++) { vf[j] += b0[j]; vf[4 + j] += b1v[j]; }
            }
            if (addC) {
                const short8 a = *(const short8*)(addC + (size_t)row * ldOut + col);
                #pragma unroll
                for (int j = 0; j < 8; j++) vf[j] += bs2f(a[j]);
            }
            short8 o;
            #pragma unroll
            for (int j = 0; j < 8; j++) {
                float x = vf[j];
                if (OUT == OM_RELU_B) x = fmaxf(x, 0.f);
                o[j] = f2bs(x);
            }
            *(short8*)(outB + (size_t)row * ldOut + col) = o;
        }
    }
}

// W[K][N] f32 -> Wt[N][Kp] bf16 (zero pad k in [K,Kp))
__global__ __launch_bounds__(256) void convert_wt(
    const float* __restrict__ W, bf16* __restrict__ Wt, int K, int Kp, int N)
{
    int i = blockIdx.x * 256 + threadIdx.x;
    if (i >= N * Kp) return;
    int n = i / Kp, k = i - n * Kp;
    Wt[i] = (k < K) ? f2b(W[(size_t)k * N + n]) : f2b(0.f);
}

// amsg[a, c..c+8) = sum_k relu(msg[a2b[a,k], c..c+8)); 16B loads, 32 thr/atom
__global__ __launch_bounds__(256) void gather_sum8(
    const bf16* __restrict__ msg, const int* __restrict__ a2b,
    bf16* __restrict__ amsg, int A)
{
    int idx = blockIdx.x * 256 + threadIdx.x;
    if (idx >= A * 32) return;
    int a = idx >> 5;
    int c = (idx & 31) * 8;
    const int* nb = a2b + (size_t)a * 6;
    float s[8] = {};
    #pragma unroll
    for (int k = 0; k < 6; k++) {
        const short8 v = *(const short8*)(msg + (size_t)nb[k] * 256 + c);
        #pragma unroll
        for (int j = 0; j < 8; j++) s[j] += fmaxf(bs2f(v[j]), 0.f);
    }
    short8 o;
    #pragma unroll
    for (int j = 0; j < 8; j++) o[j] = f2bs(s[j]);
    *(short8*)(amsg + (size_t)a * 256 + c) = o;
}

// molv[m,h] = mean over the sorted segment atom2mol==m (0 if empty)
__global__ __launch_bounds__(256) void segment_mean_kernel(
    const bf16* __restrict__ ah, const int* __restrict__ atom2mol,
    int A, float* __restrict__ molv)
{
    int m = blockIdx.x;
    int h = threadIdx.x;
    int lo = 0, hi = A;
    while (lo < hi) { int mid = (lo + hi) >> 1; if (atom2mol[mid] < m) lo = mid + 1; else hi = mid; }
    int start = lo;
    hi = A;
    while (lo < hi) { int mid = (lo + hi) >> 1; if (atom2mol[mid] <= m) lo = mid + 1; else hi = mid; }
    int end = lo;
    float s = 0.f;
    for (int a = start; a < end; a++) s += b2f(ah[(size_t)a * 256 + h]);
    float cnt = (float)(end - start);
    molv[(size_t)m * 256 + h] = s / fmaxf(cnt, 1.f);
}

extern "C" void kernel_launch(void* const* d_in, const int* in_sizes, int n_in,
                              void* d_out, int out_size, void* d_ws, size_t ws_size,
                              hipStream_t stream)
{
    const float* f_atoms  = (const float*)d_in[0];
    const float* f_bonds  = (const float*)d_in[1];
    const int*   a2b      = (const int*)d_in[2];
    const int*   b2a      = (const int*)d_in[3];
    const int*   b2revb   = (const int*)d_in[4];
    const int*   atom2mol = (const int*)d_in[5];
    const float* mol_feat = (const float*)d_in[6];
    const float* W_i      = (const float*)d_in[7];
    const float* W_h      = (const float*)d_in[8];
    const float* W_o_w    = (const float*)d_in[9];
    const float* W_o_b    = (const float*)d_in[10];
    const float* W1       = (const float*)d_in[11];
    const float* b1       = (const float*)d_in[12];
    const float* W2       = (const float*)d_in[13];
    const float* b2       = (const float*)d_in[14];

    const int A  = 100000, B = 200000, H = 256;
    const int AF = 133, BF = 147;
    const int NM = 4096, MF = 200, FH = 512, EH = 256;
    const int KpI = 160, KpH = 256, KpO = 416, Kp1 = 480, Kp2 = 512;

    char* ws = (char*)d_ws;
    bf16* buf0 = (bf16*)ws;  ws += (size_t)B * H * sizeof(bf16);      // 102.4 MB
    bf16* buf1 = (bf16*)ws;  ws += (size_t)B * H * sizeof(bf16);      // 102.4 MB
    bf16* amsg = (bf16*)ws;  ws += (size_t)A * H * sizeof(bf16);      //  51.2 MB
    float* molv = (float*)ws; ws += (size_t)NM * H * sizeof(float);   //   4.2 MB
    bf16* hbuf = (bf16*)ws;  ws += (size_t)NM * FH * sizeof(bf16);    //   4.2 MB
    bf16* WtI = (bf16*)ws;   ws += (size_t)256 * KpI * sizeof(bf16);
    bf16* WtH = (bf16*)ws;   ws += (size_t)256 * KpH * sizeof(bf16);
    bf16* WtO = (bf16*)ws;   ws += (size_t)256 * KpO * sizeof(bf16);
    bf16* Wt1 = (bf16*)ws;   ws += (size_t)512 * Kp1 * sizeof(bf16);
    bf16* Wt2 = (bf16*)ws;   ws += (size_t)256 * Kp2 * sizeof(bf16);
    // total ~265 MB

    dim3 blk(256);
    const int gsB = (B + 63) / 64;        // 3125
    const int gsA = (A + 63) / 64;        // 1563
    const int gsG = (A * 32 + 255) / 256; // 12500

    // 0. weights -> bf16 [N][Kp]
    convert_wt<<<dim3((256 * KpI + 255) / 256), blk, 0, stream>>>(W_i, WtI, BF, KpI, 256);
    convert_wt<<<dim3((256 * KpH + 255) / 256), blk, 0, stream>>>(W_h, WtH, H, KpH, 256);
    convert_wt<<<dim3((256 * KpO + 255) / 256), blk, 0, stream>>>(W_o_w, WtO, AF + H, KpO, 256);
    convert_wt<<<dim3((512 * Kp1 + 255) / 256), blk, 0, stream>>>(W1, Wt1, H + MF, Kp1, 512);
    convert_wt<<<dim3((256 * Kp2 + 255) / 256), blk, 0, stream>>>(W2, Wt2, FH, Kp2, 256);

    // 1. buf0 = f_bonds @ W_i  (pre-relu "inputs" == pre-relu msg0)
    mfma_gemm<AM_F32, OM_PRE_B, 160><<<dim3(gsB, 1), blk, 0, stream>>>(
        B, BF, 0, 256, f_bonds, nullptr, nullptr, nullptr, nullptr, nullptr,
        WtI, nullptr, nullptr, buf0, nullptr);

    // 2a. iter 1: gather from buf0 (relu-on-read => msg0); buf1 = relu(inputs + diff@W_h)
    gather_sum8<<<dim3(gsG), blk, 0, stream>>>(buf0, a2b, amsg, A);
    mfma_gemm<AM_DIFF, OM_RELU_B, 256><<<dim3(gsB, 1), blk, 0, stream>>>(
        B, H, 0, 256, nullptr, nullptr, amsg, buf0, b2a, b2revb,
        WtH, nullptr, buf0, buf1, nullptr);

    // 2b. iter 2: gather from buf1; buf0 = relu(inputs + diff@W_h) in-place
    gather_sum8<<<dim3(gsG), blk, 0, stream>>>(buf1, a2b, amsg, A);
    mfma_gemm<AM_DIFF, OM_RELU_B, 256><<<dim3(gsB, 1), blk, 0, stream>>>(
        B, H, 0, 256, nullptr, nullptr, amsg, buf1, b2a, b2revb,
        WtH, nullptr, buf0, buf0, nullptr);

    // 3. final neighbor sum (relu-on-read idempotent)
    gather_sum8<<<dim3(gsG), blk, 0, stream>>>(buf0, a2b, amsg, A);

    // 4. buf1 = relu([f_atoms | amsg] @ W_o_w + b)
    mfma_gemm<AM_CONCAT_FB, OM_RELU_B, 416><<<dim3(gsA, 1), blk, 0, stream>>>(
        A, AF + H, AF, 256, f_atoms, nullptr, amsg, nullptr, nullptr, nullptr,
        WtO, W_o_b, nullptr, buf1, nullptr);

    // 5. per-molecule mean
    segment_mean_kernel<<<dim3(NM), blk, 0, stream>>>(buf1, atom2mol, A, molv);

    // 6. hbuf = relu([molv | mol_feat] @ W1 + b1)   [4096,512] bf16
    mfma_gemm<AM_CONCAT_FF, OM_RELU_B, 480><<<dim3(NM / 64, 2), blk, 0, stream>>>(
        NM, H + MF, H, 512, molv, mol_feat, nullptr, nullptr, nullptr, nullptr,
        Wt1, b1, nullptr, hbuf, nullptr);

    // 7. out = relu(hbuf @ W2 + b2)   [4096,256] f32
    mfma_gemm<AM_BF16, OM_RELU_F, 512><<<dim3(NM / 64, 1), blk, 0, stream>>>(
        NM, FH, 0, 256, nullptr, nullptr, hbuf, nullptr, nullptr, nullptr,
        Wt2, b2, nullptr, nullptr, (float*)d_out);
}